// Round 8
// baseline (257.749 us; speedup 1.0000x reference)
//
#include <hip/hip_runtime.h>
#include <hip/hip_bf16.h>

#define H 4
#define C 32
#define CQ 128
#define NSEQ 256
#define HC 128   // H*C

typedef __bf16 bf16;
typedef __bf16 bf16x8 __attribute__((ext_vector_type(8)));
typedef __bf16 bf16x4 __attribute__((ext_vector_type(4)));
typedef __bf16 bf16x2 __attribute__((ext_vector_type(2)));
typedef float f32x4 __attribute__((ext_vector_type(4)));

#define MFMA16(a, b, c) __builtin_amdgcn_mfma_f32_16x16x32_bf16(a, b, c, 0, 0, 0)

#define LOG2E 1.4426950408889634f

// ---------------------------------------------------------------------------
// Convert the 5 weight matrices (each 128x128 f32) to bf16 in ws.
// ---------------------------------------------------------------------------
__global__ __launch_bounds__(256) void prep_weights(const float* __restrict__ wq,
                                                    const float* __restrict__ wk,
                                                    const float* __restrict__ wv,
                                                    const float* __restrict__ wg,
                                                    const float* __restrict__ wo,
                                                    bf16* __restrict__ dst) {
    const int m = blockIdx.y;
    const float* src = (m == 0) ? wq : (m == 1) ? wk : (m == 2) ? wv : (m == 3) ? wg : wo;
    int i = blockIdx.x * 256 + threadIdx.x;  // 4096 float4's per matrix
    float4 v = ((const float4*)src)[i];
    bf16x4 b = {(bf16)v.x, (bf16)v.y, (bf16)v.z, (bf16)v.w};
    ((bf16x4*)(dst + (size_t)m * 16384))[i] = b;
}

// ---------------------------------------------------------------------------
// Fully fused per-n1 kernel: projections + biased softmax attention + gating
// + output projection. One block per n1 row (grid 256, 512 threads, 8 waves).
// Wave w owns q-rows [w*32, w*32+32). Heads processed sequentially.
// amdgpu_waves_per_eu(2,2): VGPR budget 512/2 = 256 (live set ~200).
// __launch_bounds__(512,2) in R7 did NOT lift the 128 cap (VGPR stayed 128,
// spills stayed) — using the backend attributes directly.
// ---------------------------------------------------------------------------
__global__
__attribute__((amdgpu_flat_work_group_size(512, 512), amdgpu_waves_per_eu(2, 2)))
void fused_attn(const float* __restrict__ qx,
                const float* __restrict__ kvx,
                const bf16* __restrict__ wbf,
                const float* __restrict__ pair_bias,
                const float* __restrict__ mask_bias,
                float* __restrict__ out) {
    const int n1 = blockIdx.x;
    const int t = threadIdx.x;
    const int w = t >> 6, l = t & 63, lr = l & 15, lg = l >> 4;

    __shared__ bf16 xkv[256][136];   // kv_x row, bf16 (A for K/V proj)
    __shared__ bf16 klds[256][40];   // K_h  [k][c]   (B for QK^T)
    __shared__ bf16 vts[32][264];    // V_h^T [c][k]  (B for PV)
    __shared__ bf16 ps[8][2112];     // per-wave scratch: q/P/og relayout

    // ---- stage kv_x row as bf16 (coalesced: 2 threads per row) ----
    {
        const float* src = kvx + (size_t)n1 * NSEQ * CQ;
        const int row = t >> 1, c0 = (t & 1) * 64;
        #pragma unroll
        for (int j = 0; j < 8; j++) {
            const float* p = src + row * CQ + c0 + j * 8;
            float4 a = *(const float4*)p;
            float4 b = *(const float4*)(p + 4);
            bf16x8 v = {(bf16)a.x, (bf16)a.y, (bf16)a.z, (bf16)a.w,
                        (bf16)b.x, (bf16)b.y, (bf16)b.z, (bf16)b.w};
            *(bf16x8*)&xkv[row][c0 + j * 8] = v;
        }
    }

    // ---- q_x A-fragments for this wave's 32 rows (registers) ----
    bf16x8 xqf[2][4];
    {
        const float* src = qx + (size_t)n1 * NSEQ * CQ;
        #pragma unroll
        for (int qt = 0; qt < 2; qt++)
            #pragma unroll
            for (int ks = 0; ks < 4; ks++) {
                const float* p = src + (size_t)(w * 32 + qt * 16 + lr) * CQ + ks * 32 + lg * 8;
                float4 a = *(const float4*)p;
                float4 b = *(const float4*)(p + 4);
                xqf[qt][ks] = (bf16x8){(bf16)a.x, (bf16)a.y, (bf16)a.z, (bf16)a.w,
                                       (bf16)b.x, (bf16)b.y, (bf16)b.z, (bf16)b.w};
            }
    }
    __syncthreads();  // xkv ready

    bf16* myps = &ps[w][0];
    const float qscale = 0.17677669529663687f * LOG2E;  // 1/sqrt(32) * log2e
    const float* mb = mask_bias + (size_t)n1 * NSEQ;

    bf16x8 ogf[2][4];  // gated attention output A-frags: [qtile][head]

    #pragma unroll
    for (int h = 0; h < 4; h++) {
        const bf16* wq = wbf + 0 * 16384 + (size_t)h * 32 * CQ;
        const bf16* wk = wbf + 1 * 16384 + (size_t)h * 32 * CQ;
        const bf16* wv = wbf + 2 * 16384 + (size_t)h * 32 * CQ;
        const bf16* wg = wbf + 3 * 16384 + (size_t)h * 32 * CQ;

        // ---- q_h, g_h for the wave's 32 rows ----
        f32x4 qacc[2][2], gacc[2][2];
        #pragma unroll
        for (int qt = 0; qt < 2; qt++)
            #pragma unroll
            for (int nt = 0; nt < 2; nt++) { qacc[qt][nt] = (f32x4)0.f; gacc[qt][nt] = (f32x4)0.f; }
        #pragma unroll
        for (int ks = 0; ks < 4; ks++)
            #pragma unroll
            for (int nt = 0; nt < 2; nt++) {
                bf16x8 bq = *(const bf16x8*)&wq[(size_t)(nt * 16 + lr) * CQ + ks * 32 + lg * 8];
                bf16x8 bg = *(const bf16x8*)&wg[(size_t)(nt * 16 + lr) * CQ + ks * 32 + lg * 8];
                #pragma unroll
                for (int qt = 0; qt < 2; qt++) {
                    qacc[qt][nt] = MFMA16(xqf[qt][ks], bq, qacc[qt][nt]);
                    gacc[qt][nt] = MFMA16(xqf[qt][ks], bg, gacc[qt][nt]);
                }
            }

        // pack sigmoid(g) to bf16 (same D-layout as PV output -> gate later)
        bf16x4 gpk[2][2];
        #pragma unroll
        for (int qt = 0; qt < 2; qt++)
            #pragma unroll
            for (int nt = 0; nt < 2; nt++)
                #pragma unroll
                for (int r = 0; r < 4; r++)
                    gpk[qt][nt][r] =
                        (bf16)__builtin_amdgcn_rcpf(1.f + __builtin_amdgcn_exp2f(-gacc[qt][nt][r] * LOG2E));

        // ---- q relayout: D-layout -> A-frag via per-wave scratch [32][66] ----
        #pragma unroll
        for (int qt = 0; qt < 2; qt++)
            #pragma unroll
            for (int nt = 0; nt < 2; nt++)
                #pragma unroll
                for (int r = 0; r < 4; r++)
                    myps[(qt * 16 + lg * 4 + r) * 66 + nt * 16 + lr] =
                        (bf16)(qacc[qt][nt][r] * qscale);
        bf16x8 qaf[2];
        #pragma unroll
        for (int qt = 0; qt < 2; qt++)
            qaf[qt] = *(const bf16x8*)&myps[(qt * 16 + lr) * 66 + lg * 8];

        // ---- K_h, V_h for the wave's own 32 kv-rows -> shared LDS ----
        __syncthreads();  // prior head's K/V readers done
        f32x4 kacc[2][2], vacc[2][2];
        #pragma unroll
        for (int rt = 0; rt < 2; rt++)
            #pragma unroll
            for (int nt = 0; nt < 2; nt++) { kacc[rt][nt] = (f32x4)0.f; vacc[rt][nt] = (f32x4)0.f; }
        #pragma unroll
        for (int ks = 0; ks < 4; ks++) {
            bf16x8 akv0 = *(const bf16x8*)&xkv[w * 32 + lr][ks * 32 + lg * 8];
            bf16x8 akv1 = *(const bf16x8*)&xkv[w * 32 + 16 + lr][ks * 32 + lg * 8];
            #pragma unroll
            for (int nt = 0; nt < 2; nt++) {
                bf16x8 bk = *(const bf16x8*)&wk[(size_t)(nt * 16 + lr) * CQ + ks * 32 + lg * 8];
                bf16x8 bv = *(const bf16x8*)&wv[(size_t)(nt * 16 + lr) * CQ + ks * 32 + lg * 8];
                kacc[0][nt] = MFMA16(akv0, bk, kacc[0][nt]);
                kacc[1][nt] = MFMA16(akv1, bk, kacc[1][nt]);
                vacc[0][nt] = MFMA16(akv0, bv, vacc[0][nt]);
                vacc[1][nt] = MFMA16(akv1, bv, vacc[1][nt]);
            }
        }
        #pragma unroll
        for (int rt = 0; rt < 2; rt++)
            #pragma unroll
            for (int nt = 0; nt < 2; nt++) {
                #pragma unroll
                for (int r = 0; r < 4; r++)
                    klds[w * 32 + rt * 16 + lg * 4 + r][nt * 16 + lr] = (bf16)kacc[rt][nt][r];
                #pragma unroll
                for (int rp = 0; rp < 2; rp++) {
                    bf16x2 pr = {(bf16)vacc[rt][nt][rp * 2], (bf16)vacc[rt][nt][rp * 2 + 1]};
                    *(bf16x2*)&vts[nt * 16 + lr][w * 32 + rt * 16 + lg * 4 + rp * 2] = pr;
                }
            }
        __syncthreads();  // K/V ready

        // ---- attention for the wave's two 16-row q-tiles ----
        const float* pb = pair_bias + (size_t)h * NSEQ * NSEQ;
        #pragma unroll
        for (int qt = 0; qt < 2; qt++) {
            const int q0 = w * 32 + qt * 16;

            f32x4 s[16];
            #pragma unroll
            for (int kt = 0; kt < 16; kt++) {
                float mbk = mb[kt * 16 + lr] * LOG2E;
                #pragma unroll
                for (int r = 0; r < 4; r++)
                    s[kt][r] = fmaf(pb[(size_t)(q0 + lg * 4 + r) * NSEQ + kt * 16 + lr],
                                    LOG2E, mbk);
            }
            #pragma unroll
            for (int kt = 0; kt < 16; kt++) {
                bf16x8 kf = *(const bf16x8*)&klds[kt * 16 + lr][lg * 8];
                s[kt] = MFMA16(qaf[qt], kf, s[kt]);
            }

            float pinv[4];
            #pragma unroll
            for (int r = 0; r < 4; r++) {
                float mx = s[0][r];
                #pragma unroll
                for (int kt = 1; kt < 16; kt++) mx = fmaxf(mx, s[kt][r]);
                #pragma unroll
                for (int msk = 8; msk >= 1; msk >>= 1) mx = fmaxf(mx, __shfl_xor(mx, msk, 64));
                float sum = 0.f;
                #pragma unroll
                for (int kt = 0; kt < 16; kt++) {
                    float e = __builtin_amdgcn_exp2f(s[kt][r] - mx);
                    s[kt][r] = e;
                    sum += e;
                }
                #pragma unroll
                for (int msk = 8; msk >= 1; msk >>= 1) sum += __shfl_xor(sum, msk, 64);
                pinv[r] = __builtin_amdgcn_rcpf(sum);
            }

            // P relayout halves + PV (per-wave scratch, in-order within wave)
            f32x4 o[2];
            o[0] = (f32x4)0.f;
            o[1] = (f32x4)0.f;
            #pragma unroll
            for (int hf = 0; hf < 2; hf++) {
                #pragma unroll
                for (int kt2 = 0; kt2 < 8; kt2++)
                    #pragma unroll
                    for (int r = 0; r < 4; r++)
                        myps[(lg * 4 + r) * 132 + kt2 * 16 + lr] =
                            (bf16)(s[hf * 8 + kt2][r] * pinv[r]);
                #pragma unroll
                for (int kh = 0; kh < 4; kh++) {
                    bf16x8 pf = *(const bf16x8*)&myps[lr * 132 + kh * 32 + lg * 8];
                    #pragma unroll
                    for (int ct = 0; ct < 2; ct++) {
                        bf16x8 vf = *(const bf16x8*)&vts[ct * 16 + lr][hf * 128 + kh * 32 + lg * 8];
                        o[ct] = MFMA16(pf, vf, o[ct]);
                    }
                }
            }

            // gate + relayout og to A-frag; STATIC store target per head
            // (dynamic ogf[qt][h] would go to scratch if h-loop doesn't unroll)
            #pragma unroll
            for (int ct = 0; ct < 2; ct++)
                #pragma unroll
                for (int r = 0; r < 4; r++)
                    myps[(lg * 4 + r) * 66 + ct * 16 + lr] =
                        (bf16)(o[ct][r] * (float)gpk[qt][ct][r]);
            bf16x8 ov = *(const bf16x8*)&myps[lr * 66 + lg * 8];
            if (h == 0)      ogf[qt][0] = ov;
            else if (h == 1) ogf[qt][1] = ov;
            else if (h == 2) ogf[qt][2] = ov;
            else             ogf[qt][3] = ov;
        }
    }

    // ---- output projection: out = og @ w_o^T (f32) ----
    const bf16* wo = wbf + 4 * 16384;
    float* outp = out + (size_t)n1 * NSEQ * CQ;
    #pragma unroll
    for (int qt = 0; qt < 2; qt++)
        #pragma unroll
        for (int nt = 0; nt < 8; nt++) {
            f32x4 acc = (f32x4)0.f;
            #pragma unroll
            for (int ks = 0; ks < 4; ks++) {
                bf16x8 b = *(const bf16x8*)&wo[(size_t)(nt * 16 + lr) * CQ + ks * 32 + lg * 8];
                acc = MFMA16(ogf[qt][ks], b, acc);
            }
            #pragma unroll
            for (int r = 0; r < 4; r++)
                outp[(size_t)(w * 32 + qt * 16 + lg * 4 + r) * CQ + nt * 16 + lr] = acc[r];
        }
}

// ---------------------------------------------------------------------------
extern "C" void kernel_launch(void* const* d_in, const int* in_sizes, int n_in,
                              void* d_out, int out_size, void* d_ws, size_t ws_size,
                              hipStream_t stream) {
    const float* q_x = (const float*)d_in[0];
    const float* kv_x = (const float*)d_in[1];
    const float* mask_bias = (const float*)d_in[2];
    const float* pair_bias = (const float*)d_in[3];
    const float* w_q = (const float*)d_in[4];
    const float* w_k = (const float*)d_in[5];
    const float* w_v = (const float*)d_in[6];
    const float* w_g = (const float*)d_in[7];
    const float* w_o = (const float*)d_in[8];

    bf16* wbf = (bf16*)d_ws;  // [5][16384] bf16: q,k,v,g,o

    prep_weights<<<dim3(16, 5), 256, 0, stream>>>(w_q, w_k, w_v, w_g, w_o, wbf);
    fused_attn<<<dim3(NSEQ), 512, 0, stream>>>(q_x, kv_x, wbf, pair_bias, mask_bias,
                                               (float*)d_out);
}

// Round 9
// 93.286 us; speedup vs baseline: 2.7630x; 2.7630x over previous
//
#include <hip/hip_runtime.h>
#include <hip/hip_bf16.h>

#define H 4
#define C 32
#define CQ 128
#define NSEQ 256
#define HC 128   // H*C

typedef __bf16 bf16;
typedef __bf16 bf16x8 __attribute__((ext_vector_type(8)));
typedef __bf16 bf16x4 __attribute__((ext_vector_type(4)));
typedef float f32x4 __attribute__((ext_vector_type(4)));

#define MFMA16(a, b, c) __builtin_amdgcn_mfma_f32_16x16x32_bf16(a, b, c, 0, 0, 0)

#define LOG2E 1.4426950408889634f

// ---------------------------------------------------------------------------
// Convert the 5 weight matrices (each 128x128 f32) to bf16 in ws.
// ---------------------------------------------------------------------------
__global__ __launch_bounds__(256) void prep_weights(const float* __restrict__ wq,
                                                    const float* __restrict__ wk,
                                                    const float* __restrict__ wv,
                                                    const float* __restrict__ wg,
                                                    const float* __restrict__ wo,
                                                    bf16* __restrict__ dst) {
    const int m = blockIdx.y;
    const float* src = (m == 0) ? wq : (m == 1) ? wk : (m == 2) ? wv : (m == 3) ? wg : wo;
    int i = blockIdx.x * 256 + threadIdx.x;  // 4096 float4's per matrix
    float4 v = ((const float4*)src)[i];
    bf16x4 b = {(bf16)v.x, (bf16)v.y, (bf16)v.z, (bf16)v.w};
    ((bf16x4*)(dst + (size_t)m * 16384))[i] = b;
}

// ---------------------------------------------------------------------------
// Dual projection v2: weights in LDS (staged once per block, amortized over
// 256 rows), A-fragments direct from global f32. No B-register residency ->
// nothing for the allocator to undo. 4 chunks of 64 rows per block.
// mode 0: q = (q_x@w_q^T)*(qscale*log2e), g = sigmoid(q_x@w_g^T)
// mode 1: k = kv_x@w_k^T, v = kv_x@w_v^T
// ---------------------------------------------------------------------------
__global__ __launch_bounds__(256) void proj_all(const float* __restrict__ qx,
                                                const float* __restrict__ kvx,
                                                const bf16* __restrict__ wbf,
                                                bf16* __restrict__ qo,
                                                bf16* __restrict__ go,
                                                bf16* __restrict__ ko,
                                                bf16* __restrict__ vo) {
    __shared__ bf16 w1s[128][136];
    __shared__ bf16 w2s[128][136];

    const int t = threadIdx.x;
    const int mode = blockIdx.y;

    const float* x = mode ? kvx : qx;
    const bf16* w1 = wbf + (mode ? 1 : 0) * 16384;  // w_k : w_q
    const bf16* w2 = wbf + (mode ? 2 : 3) * 16384;  // w_v : w_g
    bf16* o1 = mode ? ko : qo;
    bf16* o2 = mode ? vo : go;

    // stage both weight matrices (bf16x8 per thread-iter; 16 iters)
    #pragma unroll
    for (int i = t; i < 2048; i += 256) {
        int row = i >> 4, col = (i & 15) * 8;
        *(bf16x8*)&w1s[row][col] = *(const bf16x8*)&w1[row * CQ + col];
        *(bf16x8*)&w2s[row][col] = *(const bf16x8*)&w2[row * CQ + col];
    }
    __syncthreads();

    const int w = t >> 6, l = t & 63, lr = l & 15, lg = l >> 4;
    const float qscale = 0.17677669529663687f * LOG2E;  // 1/sqrt(32) * log2e

    for (int it = 0; it < 4; it++) {
        const int row0 = blockIdx.x * 256 + it * 64 + w * 16;

        // A-fragments direct from global f32 (8 independent float4 loads)
        bf16x8 a[4];
        #pragma unroll
        for (int ks = 0; ks < 4; ks++) {
            const float* p = x + (size_t)(row0 + lr) * CQ + ks * 32 + lg * 8;
            float4 lo = *(const float4*)p;
            float4 hi = *(const float4*)(p + 4);
            a[ks] = (bf16x8){(bf16)lo.x, (bf16)lo.y, (bf16)lo.z, (bf16)lo.w,
                             (bf16)hi.x, (bf16)hi.y, (bf16)hi.z, (bf16)hi.w};
        }

        f32x4 acc1[8], acc2[8];
        #pragma unroll
        for (int nt = 0; nt < 8; nt++) { acc1[nt] = (f32x4)0.f; acc2[nt] = (f32x4)0.f; }

        #pragma unroll
        for (int nt = 0; nt < 8; nt++) {
            #pragma unroll
            for (int ks = 0; ks < 4; ks++) {
                bf16x8 b1 = *(const bf16x8*)&w1s[nt * 16 + lr][ks * 32 + lg * 8];
                acc1[nt] = MFMA16(a[ks], b1, acc1[nt]);
            }
            #pragma unroll
            for (int ks = 0; ks < 4; ks++) {
                bf16x8 b2 = *(const bf16x8*)&w2s[nt * 16 + lr][ks * 32 + lg * 8];
                acc2[nt] = MFMA16(a[ks], b2, acc2[nt]);
            }
        }

        #pragma unroll
        for (int nt = 0; nt < 8; nt++) {
            #pragma unroll
            for (int r = 0; r < 4; r++) {
                const int row = row0 + lg * 4 + r;
                const int col = nt * 16 + lr;
                float v1 = acc1[nt][r], v2 = acc2[nt][r];
                if (mode == 0) {
                    v1 *= qscale;
                    v2 = __builtin_amdgcn_rcpf(1.f + __builtin_amdgcn_exp2f(-v2 * LOG2E));
                }
                o1[(size_t)row * HC + col] = (bf16)v1;
                o2[(size_t)row * HC + col] = (bf16)v2;
            }
        }
    }
}

// ---------------------------------------------------------------------------
// Attention per (qc, n1, h): 64 q-rows x 256 k, C=32. Linear 4096-block grid
// with chunked XCD swizzle so the 4 qc-blocks of one (n1,h) land on the SAME
// XCD. Scores in log2 domain; softmax via exp2; PV in two 128-k halves
// through a per-wave P tile. (Unchanged from R3 — proven.)
// ---------------------------------------------------------------------------
__global__ __launch_bounds__(256) void attn_kernel(const bf16* __restrict__ qw,
                                                   const bf16* __restrict__ kw,
                                                   const bf16* __restrict__ vw,
                                                   const bf16* __restrict__ gw,
                                                   const float* __restrict__ pair_bias,
                                                   const float* __restrict__ mask_bias,
                                                   bf16* __restrict__ ow) {
    const int wg = blockIdx.x;
    const int swz = ((wg & 7) << 9) + (wg >> 3);
    const int qc = swz & 3;
    const int n1 = (swz >> 2) & 255;
    const int h = swz >> 10;

    __shared__ bf16 klds[256][40];   // K slice [k][c], stride 20 dw
    __shared__ bf16 vts[32][256];    // V^T, col = k ^ 16*((c>>3)&3) ^ 8*(c&7)
    __shared__ bf16 ps[4][16][132];  // per-wave P tile

    const int t = threadIdx.x;

    {
        const size_t base = ((size_t)n1 * NSEQ) * HC + (size_t)h * C;
        const int rr = t >> 2, cc4 = t & 3, ch = cc4 * 8;
        #pragma unroll
        for (int p = 0; p < 4; p++) {
            int row = p * 64 + rr;
            bf16x8 kv = *(const bf16x8*)&kw[base + (size_t)row * HC + ch];
            *(bf16x8*)&klds[row][ch] = kv;
            bf16x8 vv = *(const bf16x8*)&vw[base + (size_t)row * HC + ch];
            #pragma unroll
            for (int j = 0; j < 8; j++) {
                int colw = row ^ (cc4 << 4) ^ (j << 3);
                vts[ch + j][colw] = vv[j];
            }
        }
    }

    const int w = t >> 6, l = t & 63, lr = l & 15, lg = l >> 4;
    const int qbase = qc * 64 + w * 16;

    bf16x8 qf = *(const bf16x8*)&qw[((size_t)(n1 * NSEQ + qbase + lr)) * HC + h * C + lg * 8];

    const float* pb = pair_bias + (size_t)h * NSEQ * NSEQ;
    const float* mb = mask_bias + (size_t)n1 * NSEQ;

    __syncthreads();

    f32x4 s[16];
    #pragma unroll
    for (int kt = 0; kt < 16; kt++) {
        float mbk = mb[kt * 16 + lr] * LOG2E;
        #pragma unroll
        for (int r = 0; r < 4; r++)
            s[kt][r] = fmaf(pb[(size_t)(qbase + lg * 4 + r) * NSEQ + kt * 16 + lr],
                            LOG2E, mbk);
    }
    #pragma unroll
    for (int kt = 0; kt < 16; kt++) {
        bf16x8 kf = *(const bf16x8*)&klds[kt * 16 + lr][lg * 8];
        s[kt] = MFMA16(qf, kf, s[kt]);
    }

    float pinv[4];
    #pragma unroll
    for (int r = 0; r < 4; r++) {
        float mx = s[0][r];
        #pragma unroll
        for (int kt = 1; kt < 16; kt++) mx = fmaxf(mx, s[kt][r]);
        #pragma unroll
        for (int msk = 8; msk >= 1; msk >>= 1) mx = fmaxf(mx, __shfl_xor(mx, msk, 64));
        float sum = 0.f;
        #pragma unroll
        for (int kt = 0; kt < 16; kt++) {
            float e = __builtin_amdgcn_exp2f(s[kt][r] - mx);
            s[kt][r] = e;
            sum += e;
        }
        #pragma unroll
        for (int msk = 8; msk >= 1; msk >>= 1) sum += __shfl_xor(sum, msk, 64);
        pinv[r] = __builtin_amdgcn_rcpf(sum);
    }

    f32x4 o[2];
    o[0] = (f32x4)0.f;
    o[1] = (f32x4)0.f;
    #pragma unroll
    for (int hf = 0; hf < 2; hf++) {
        #pragma unroll
        for (int kt2 = 0; kt2 < 8; kt2++) {
            #pragma unroll
            for (int r = 0; r < 4; r++)
                ps[w][lg * 4 + r][kt2 * 16 + lr] = (bf16)(s[hf * 8 + kt2][r] * pinv[r]);
        }
        #pragma unroll
        for (int kh = 0; kh < 4; kh++) {
            bf16x8 pf = *(const bf16x8*)&ps[w][lr][kh * 32 + lg * 8];
            #pragma unroll
            for (int ct = 0; ct < 2; ct++) {
                int g2 = (2 * ct + (lr >> 3)) & 3;
                int col0 = (hf * 128 + kh * 32 + lg * 8) ^ (g2 << 4) ^ ((lr & 7) << 3);
                bf16x8 vf = *(const bf16x8*)&vts[ct * 16 + lr][col0];
                o[ct] = MFMA16(pf, vf, o[ct]);
            }
        }
    }

    #pragma unroll
    for (int ct = 0; ct < 2; ct++) {
        #pragma unroll
        for (int r = 0; r < 4; r++) {
            size_t idx = ((size_t)(n1 * NSEQ + qbase + lg * 4 + r)) * HC + (size_t)h * C +
                         ct * 16 + lr;
            float gv = (float)gw[idx];
            ow[idx] = (bf16)(o[ct][r] * gv);
        }
    }
}

// ---------------------------------------------------------------------------
// Output projection v2: w_o in LDS (staged once, 256 rows/block), og A-frags
// direct from global bf16. out[m, c] = sum_d og[m, d] * w_o[c, d] (f32 out).
// ---------------------------------------------------------------------------
__global__ __launch_bounds__(256) void out_proj(const bf16* __restrict__ og,
                                                const bf16* __restrict__ wo,
                                                float* __restrict__ out) {
    __shared__ bf16 ws[128][136];
    const int t = threadIdx.x;

    #pragma unroll
    for (int i = t; i < 2048; i += 256) {
        int row = i >> 4, col = (i & 15) * 8;
        *(bf16x8*)&ws[row][col] = *(const bf16x8*)&wo[row * CQ + col];
    }
    __syncthreads();

    const int w = t >> 6, l = t & 63, lr = l & 15, lg = l >> 4;

    for (int it = 0; it < 4; it++) {
        const int row0 = blockIdx.x * 256 + it * 64 + w * 16;

        bf16x8 a[4];
        #pragma unroll
        for (int ks = 0; ks < 4; ks++)
            a[ks] = *(const bf16x8*)&og[(size_t)(row0 + lr) * HC + ks * 32 + lg * 8];

        f32x4 acc[8];
        #pragma unroll
        for (int nt = 0; nt < 8; nt++) acc[nt] = (f32x4)0.f;
        #pragma unroll
        for (int nt = 0; nt < 8; nt++) {
            #pragma unroll
            for (int ks = 0; ks < 4; ks++) {
                bf16x8 b = *(const bf16x8*)&ws[nt * 16 + lr][ks * 32 + lg * 8];
                acc[nt] = MFMA16(a[ks], b, acc[nt]);
            }
        }

        #pragma unroll
        for (int nt = 0; nt < 8; nt++)
            #pragma unroll
            for (int r = 0; r < 4; r++)
                out[(size_t)(row0 + lg * 4 + r) * CQ + nt * 16 + lr] = acc[nt][r];
    }
}

// ---------------------------------------------------------------------------
extern "C" void kernel_launch(void* const* d_in, const int* in_sizes, int n_in,
                              void* d_out, int out_size, void* d_ws, size_t ws_size,
                              hipStream_t stream) {
    const float* q_x = (const float*)d_in[0];
    const float* kv_x = (const float*)d_in[1];
    const float* mask_bias = (const float*)d_in[2];
    const float* pair_bias = (const float*)d_in[3];
    const float* w_q = (const float*)d_in[4];
    const float* w_k = (const float*)d_in[5];
    const float* w_v = (const float*)d_in[6];
    const float* w_g = (const float*)d_in[7];
    const float* w_o = (const float*)d_in[8];

    const size_t M = (size_t)NSEQ * NSEQ;  // 65536
    bf16* wbf = (bf16*)d_ws;               // [5][16384] bf16: q,k,v,g,o
    bf16* qws = wbf + 5 * 16384;
    bf16* gws = qws + M * HC;
    bf16* kws = gws + M * HC;
    bf16* vws = kws + M * HC;
    bf16* ows = vws + M * HC;

    prep_weights<<<dim3(16, 5), 256, 0, stream>>>(w_q, w_k, w_v, w_g, w_o, wbf);
    proj_all<<<dim3(256, 2), 256, 0, stream>>>(q_x, kv_x, wbf, qws, gws, kws, vws);
    attn_kernel<<<dim3(4096), 256, 0, stream>>>(qws, kws, vws, gws, pair_bias,
                                                mask_bias, ows);
    out_proj<<<dim3(256), 256, 0, stream>>>(ows, wbf + 4 * 16384, (float*)d_out);
}